// Round 3
// baseline (625.696 us; speedup 1.0000x reference)
//
#include <hip/hip_runtime.h>

#define NN 65536
#define NE 262144
#define NG 2048

// ---------------- gate logits: g_all[n] = (relu(x@gw1+gb1))@gw2 + gb2 --------
__global__ __launch_bounds__(256) void k_gate(const float* __restrict__ x,
    const float* __restrict__ gw1, const float* __restrict__ gb1,
    const float* __restrict__ gw2, const float* __restrict__ gb2,
    float* __restrict__ g_all)
{
    __shared__ float s_w[256];
    __shared__ float s_b[16];
    __shared__ float s_w2[16];
    __shared__ float s_b2;
    int tid = threadIdx.x;
    s_w[tid & 255] = gw1[tid & 255];
    if (tid < 16) { s_b[tid] = gb1[tid]; s_w2[tid] = gw2[tid]; }
    if (tid == 0) s_b2 = gb2[0];
    __syncthreads();
    int n = blockIdx.x * 256 + tid;
    if (n >= NN) return;
    float xv[16];
    const float4* xp = (const float4*)(x + (size_t)n * 16);
#pragma unroll
    for (int i = 0; i < 4; ++i) {
        float4 t = xp[i];
        xv[4*i] = t.x; xv[4*i+1] = t.y; xv[4*i+2] = t.z; xv[4*i+3] = t.w;
    }
    float g = s_b2;
#pragma unroll
    for (int j = 0; j < 16; ++j) {
        float a = s_b[j];
#pragma unroll
        for (int i = 0; i < 16; ++i) a += xv[i] * s_w[i*16 + j];
        g += fmaxf(a, 0.f) * s_w2[j];
    }
    g_all[n] = g;
}

// ---------------- graph boundary offsets (batch is sorted) ------------------
__global__ void k_goffsets(const int* __restrict__ batch, int* __restrict__ goffs)
{
    int g = blockIdx.x * blockDim.x + threadIdx.x;
    if (g > NG) return;
    int lo = 0, hi = NN;
    while (lo < hi) {
        int mid = (lo + hi) >> 1;
        if (batch[mid] < g) lo = mid + 1; else hi = mid;
    }
    goffs[g] = lo;
}

// ---------------- attention pool over raw x ---------------------------------
__global__ __launch_bounds__(64) void k_attpool(const float* __restrict__ x,
    const float* __restrict__ g_all, const int* __restrict__ goffs,
    float* __restrict__ x_att)
{
    int g = blockIdx.x;
    int lane = threadIdx.x;
    int s = goffs[g], e = goffs[g + 1];
    if (s >= e) {
        if (lane < 16) x_att[g*16 + lane] = 0.f;
        return;
    }
    float m = -1e30f;
    for (int i = s + lane; i < e; i += 64) m = fmaxf(m, g_all[i]);
#pragma unroll
    for (int d = 32; d; d >>= 1) m = fmaxf(m, __shfl_xor(m, d));
    float sum = 0.f;
    for (int i = s + lane; i < e; i += 64) sum += expf(g_all[i] - m);
#pragma unroll
    for (int d = 32; d; d >>= 1) sum += __shfl_xor(sum, d);
    float inv = 1.f / sum;
    int f = lane & 15, sub = lane >> 4;  // 4 node-slots x 16 features
    float acc = 0.f;
    for (int i = s + sub; i < e; i += 4) {
        float w = expf(g_all[i] - m) * inv;
        acc += w * x[(size_t)i*16 + f];
    }
    acc += __shfl_xor(acc, 16);
    acc += __shfl_xor(acc, 32);
    if (lane < 16) x_att[g*16 + f] = acc;
}

// ---------------- CSR build: histogram / scan / scatter ----------------------
__global__ __launch_bounds__(256) void k_hist(const int* __restrict__ ei, int* __restrict__ cnt)
{
    int e = blockIdx.x * 256 + threadIdx.x;
    if (e >= NE) return;
    atomicAdd(&cnt[ei[NE + e]], 1);
}

__global__ __launch_bounds__(256) void k_scan_blk(const int* __restrict__ cnt,
    int* __restrict__ offs, int* __restrict__ bsum)
{
    __shared__ int s[256];
    int t = threadIdx.x, b = blockIdx.x;
    int v = cnt[b*256 + t];
    s[t] = v;
    __syncthreads();
#pragma unroll
    for (int d = 1; d < 256; d <<= 1) {
        int add = (t >= d) ? s[t - d] : 0;
        __syncthreads();
        s[t] += add;
        __syncthreads();
    }
    offs[b*256 + t] = s[t] - v;          // exclusive within block
    if (t == 255) bsum[b] = s[255];
}

__global__ __launch_bounds__(256) void k_scan_top(const int* __restrict__ bsum,
    int* __restrict__ boff)
{
    __shared__ int s[256];
    int t = threadIdx.x;
    int v = bsum[t];
    s[t] = v;
    __syncthreads();
#pragma unroll
    for (int d = 1; d < 256; d <<= 1) {
        int add = (t >= d) ? s[t - d] : 0;
        __syncthreads();
        s[t] += add;
        __syncthreads();
    }
    boff[t] = s[t] - v;                  // exclusive
}

__global__ __launch_bounds__(256) void k_scan_add(int* __restrict__ offs,
    const int* __restrict__ boff)
{
    int i = blockIdx.x * 256 + threadIdx.x;
    if (i == 0) offs[NN] = NE;
    if (i >= NN) return;
    offs[i] += boff[i >> 8];
}

__global__ __launch_bounds__(256) void k_scatter(const int* __restrict__ ei,
    const int* __restrict__ offs, int* __restrict__ cur, int* __restrict__ eperm)
{
    int e = blockIdx.x * 256 + threadIdx.x;
    if (e >= NE) return;
    int d = ei[NE + e];
    int pos = offs[d] + atomicAdd(&cur[d], 1);
    eperm[pos] = e;
}

// ---------------- conv1 edge kernel: NNConv(16 -> 32), msg output ------------
// 4 edges/thread; w2 reads split LDS (even q) / global VMEM (odd q) so the two
// pipes carry half the weight-broadcast traffic each. Each b128 read feeds 16 FMAs.
__global__ __launch_bounds__(256, 1) void k_conv1(
    const float* __restrict__ x, const float* __restrict__ ea,
    const int* __restrict__ ei, const int* __restrict__ eperm,
    const float* __restrict__ w1, const float* __restrict__ b1,
    const float* __restrict__ w2, const float* __restrict__ b2,
    float* __restrict__ msg)
{
    __shared__ float  s_w1[96];
    __shared__ float  s_b1[16];
    __shared__ float4 s_w2[2048];   // [16 k][16 i][8 q] float4 (w2 row k = 512 f)
    __shared__ float4 s_b2[128];    // [16 i][8 q]
    const int tid = threadIdx.x;
    for (int i = tid; i < 2048; i += 256) s_w2[i] = ((const float4*)w2)[i];
    for (int i = tid; i < 96;   i += 256) s_w1[i] = w1[i];
    if (tid < 16)  s_b1[tid] = b1[tid];
    if (tid < 128) s_b2[tid] = ((const float4*)b2)[tid];
    __syncthreads();

    const int lane0 = (int)__builtin_amdgcn_mbcnt_lo(0u, 0u);   // ==0, opaque: forces VMEM path
    const float4* __restrict__ gw2 = (const float4*)w2 + lane0;

    const int pb = blockIdx.x * 1024 + tid;
    int ep0 = eperm[pb], ep1 = eperm[pb + 256], ep2 = eperm[pb + 512], ep3 = eperm[pb + 768];

    float h[4][16];
    {
        float a0[6], a1[6], a2[6], a3[6];
#pragma unroll
        for (int t = 0; t < 6; ++t) {
            a0[t] = ea[(size_t)ep0*6 + t];
            a1[t] = ea[(size_t)ep1*6 + t];
            a2[t] = ea[(size_t)ep2*6 + t];
            a3[t] = ea[(size_t)ep3*6 + t];
        }
#pragma unroll
        for (int j = 0; j < 16; ++j) {
            float c0 = s_b1[j], c1 = c0, c2 = c0, c3 = c0;
#pragma unroll
            for (int t = 0; t < 6; ++t) {
                float w = s_w1[t*16 + j];
                c0 += a0[t]*w; c1 += a1[t]*w; c2 += a2[t]*w; c3 += a3[t]*w;
            }
            h[0][j] = fmaxf(c0, 0.f); h[1][j] = fmaxf(c1, 0.f);
            h[2][j] = fmaxf(c2, 0.f); h[3][j] = fmaxf(c3, 0.f);
        }
    }

    const float4* xr0 = (const float4*)(x + (size_t)ei[ep0] * 16);
    const float4* xr1 = (const float4*)(x + (size_t)ei[ep1] * 16);
    const float4* xr2 = (const float4*)(x + (size_t)ei[ep2] * 16);
    const float4* xr3 = (const float4*)(x + (size_t)ei[ep3] * 16);

    float4 m0[8], m1[8], m2[8], m3[8];
#pragma unroll
    for (int q = 0; q < 8; ++q) {
        m0[q] = make_float4(0.f,0.f,0.f,0.f); m1[q] = m0[q]; m2[q] = m0[q]; m3[q] = m0[q];
    }

#pragma unroll
    for (int i4 = 0; i4 < 4; ++i4) {
        float4 va = xr0[i4], vb = xr1[i4], vc = xr2[i4], vd = xr3[i4];
        float x0[4] = {va.x, va.y, va.z, va.w};
        float x1[4] = {vb.x, vb.y, vb.z, vb.w};
        float x2[4] = {vc.x, vc.y, vc.z, vc.w};
        float x3[4] = {vd.x, vd.y, vd.z, vd.w};
#pragma unroll
        for (int ii = 0; ii < 4; ++ii) {
            const int i = i4*4 + ii;
            const float xi0 = x0[ii], xi1 = x1[ii], xi2 = x2[ii], xi3 = x3[ii];
#pragma unroll
            for (int q = 0; q < 8; ++q) {
                float4 br = s_b2[i*8 + q];
                float4 w0 = br, w1v = br, w2v = br, w3 = br;
#pragma unroll
                for (int k = 0; k < 16; ++k) {
                    float4 w;
                    if (q & 1) w = gw2[k*128 + i*8 + q];
                    else       w = s_w2[k*128 + i*8 + q];
                    w0.x  += h[0][k]*w.x; w0.y  += h[0][k]*w.y; w0.z  += h[0][k]*w.z; w0.w  += h[0][k]*w.w;
                    w1v.x += h[1][k]*w.x; w1v.y += h[1][k]*w.y; w1v.z += h[1][k]*w.z; w1v.w += h[1][k]*w.w;
                    w2v.x += h[2][k]*w.x; w2v.y += h[2][k]*w.y; w2v.z += h[2][k]*w.z; w2v.w += h[2][k]*w.w;
                    w3.x  += h[3][k]*w.x; w3.y  += h[3][k]*w.y; w3.z  += h[3][k]*w.z; w3.w  += h[3][k]*w.w;
                }
                m0[q].x += xi0*w0.x;  m0[q].y += xi0*w0.y;  m0[q].z += xi0*w0.z;  m0[q].w += xi0*w0.w;
                m1[q].x += xi1*w1v.x; m1[q].y += xi1*w1v.y; m1[q].z += xi1*w1v.z; m1[q].w += xi1*w1v.w;
                m2[q].x += xi2*w2v.x; m2[q].y += xi2*w2v.y; m2[q].z += xi2*w2v.z; m2[q].w += xi2*w2v.w;
                m3[q].x += xi3*w3.x;  m3[q].y += xi3*w3.y;  m3[q].z += xi3*w3.z;  m3[q].w += xi3*w3.w;
            }
        }
    }

    float4* mp0 = (float4*)(msg + (size_t)pb * 32);
    float4* mp1 = (float4*)(msg + (size_t)(pb + 256) * 32);
    float4* mp2 = (float4*)(msg + (size_t)(pb + 512) * 32);
    float4* mp3 = (float4*)(msg + (size_t)(pb + 768) * 32);
#pragma unroll
    for (int q = 0; q < 8; ++q) mp0[q] = m0[q];
#pragma unroll
    for (int q = 0; q < 8; ++q) mp1[q] = m1[q];
#pragma unroll
    for (int q = 0; q < 8; ++q) mp2[q] = m2[q];
#pragma unroll
    for (int q = 0; q < 8; ++q) mp3[q] = m3[q];
}

// ---------------- reduce1: h1 = relu(segsum(msg) + x@root1 + bias1) ----------
__global__ __launch_bounds__(256) void k_reduce1(
    const float* __restrict__ msg, const int* __restrict__ offs,
    const float* __restrict__ x, const float* __restrict__ root,
    const float* __restrict__ bias, float* __restrict__ h1)
{
    __shared__ float s_r[512];   // [16][32]
    __shared__ float s_b[32];
    int tid = threadIdx.x;
    for (int i = tid; i < 512; i += 256) s_r[i] = root[i];
    if (tid < 32) s_b[tid] = bias[tid];
    __syncthreads();
    int gid = blockIdx.x * 256 + tid;
    int n = gid >> 3, q = gid & 7;       // 8 float4 columns per node
    int s = offs[n], e = offs[n + 1];
    float4 acc = make_float4(s_b[4*q], s_b[4*q+1], s_b[4*q+2], s_b[4*q+3]);
    const float4* s_r4 = (const float4*)s_r;   // [16][8]
    const float* xp = x + (size_t)n * 16;
#pragma unroll
    for (int i = 0; i < 16; ++i) {
        float xi = xp[i];
        float4 w = s_r4[i*8 + q];
        acc.x += xi*w.x; acc.y += xi*w.y; acc.z += xi*w.z; acc.w += xi*w.w;
    }
    for (int p = s; p < e; ++p) {
        float4 mr = ((const float4*)(msg + (size_t)p * 32))[q];
        acc.x += mr.x; acc.y += mr.y; acc.z += mr.z; acc.w += mr.w;
    }
    acc.x = fmaxf(acc.x, 0.f); acc.y = fmaxf(acc.y, 0.f);
    acc.z = fmaxf(acc.z, 0.f); acc.w = fmaxf(acc.w, 0.f);
    ((float4*)(h1 + (size_t)n * 32))[q] = acc;
}

// ---------------- conv2 edge kernel: NNConv(32 -> 16), msg output ------------
__global__ __launch_bounds__(256, 1) void k_conv2(
    const float* __restrict__ x, const float* __restrict__ ea,
    const int* __restrict__ ei, const int* __restrict__ eperm,
    const float* __restrict__ w1, const float* __restrict__ b1,
    const float* __restrict__ w2, const float* __restrict__ b2,
    float* __restrict__ msg)
{
    __shared__ float  s_w1[96];
    __shared__ float  s_b1[16];
    __shared__ float4 s_w2[2048];   // [16 k][32 i][4 q] float4
    __shared__ float4 s_b2[128];    // [32 i][4 q]
    const int tid = threadIdx.x;
    for (int i = tid; i < 2048; i += 256) s_w2[i] = ((const float4*)w2)[i];
    for (int i = tid; i < 96;   i += 256) s_w1[i] = w1[i];
    if (tid < 16)  s_b1[tid] = b1[tid];
    if (tid < 128) s_b2[tid] = ((const float4*)b2)[tid];
    __syncthreads();

    const int lane0 = (int)__builtin_amdgcn_mbcnt_lo(0u, 0u);
    const float4* __restrict__ gw2 = (const float4*)w2 + lane0;

    const int pb = blockIdx.x * 1024 + tid;
    int ep0 = eperm[pb], ep1 = eperm[pb + 256], ep2 = eperm[pb + 512], ep3 = eperm[pb + 768];

    float h[4][16];
    {
        float a0[6], a1[6], a2[6], a3[6];
#pragma unroll
        for (int t = 0; t < 6; ++t) {
            a0[t] = ea[(size_t)ep0*6 + t];
            a1[t] = ea[(size_t)ep1*6 + t];
            a2[t] = ea[(size_t)ep2*6 + t];
            a3[t] = ea[(size_t)ep3*6 + t];
        }
#pragma unroll
        for (int j = 0; j < 16; ++j) {
            float c0 = s_b1[j], c1 = c0, c2 = c0, c3 = c0;
#pragma unroll
            for (int t = 0; t < 6; ++t) {
                float w = s_w1[t*16 + j];
                c0 += a0[t]*w; c1 += a1[t]*w; c2 += a2[t]*w; c3 += a3[t]*w;
            }
            h[0][j] = fmaxf(c0, 0.f); h[1][j] = fmaxf(c1, 0.f);
            h[2][j] = fmaxf(c2, 0.f); h[3][j] = fmaxf(c3, 0.f);
        }
    }

    const float4* xr0 = (const float4*)(x + (size_t)ei[ep0] * 32);
    const float4* xr1 = (const float4*)(x + (size_t)ei[ep1] * 32);
    const float4* xr2 = (const float4*)(x + (size_t)ei[ep2] * 32);
    const float4* xr3 = (const float4*)(x + (size_t)ei[ep3] * 32);

    float4 m0[4], m1[4], m2[4], m3[4];
#pragma unroll
    for (int q = 0; q < 4; ++q) {
        m0[q] = make_float4(0.f,0.f,0.f,0.f); m1[q] = m0[q]; m2[q] = m0[q]; m3[q] = m0[q];
    }

#pragma unroll
    for (int i4 = 0; i4 < 8; ++i4) {
        float4 va = xr0[i4], vb = xr1[i4], vc = xr2[i4], vd = xr3[i4];
        float x0[4] = {va.x, va.y, va.z, va.w};
        float x1[4] = {vb.x, vb.y, vb.z, vb.w};
        float x2[4] = {vc.x, vc.y, vc.z, vc.w};
        float x3[4] = {vd.x, vd.y, vd.z, vd.w};
#pragma unroll
        for (int ii = 0; ii < 4; ++ii) {
            const int i = i4*4 + ii;
            const float xi0 = x0[ii], xi1 = x1[ii], xi2 = x2[ii], xi3 = x3[ii];
#pragma unroll
            for (int q = 0; q < 4; ++q) {
                float4 br = s_b2[i*4 + q];
                float4 w0 = br, w1v = br, w2v = br, w3 = br;
#pragma unroll
                for (int k = 0; k < 16; ++k) {
                    float4 w;
                    if (q & 1) w = gw2[k*128 + i*4 + q];
                    else       w = s_w2[k*128 + i*4 + q];
                    w0.x  += h[0][k]*w.x; w0.y  += h[0][k]*w.y; w0.z  += h[0][k]*w.z; w0.w  += h[0][k]*w.w;
                    w1v.x += h[1][k]*w.x; w1v.y += h[1][k]*w.y; w1v.z += h[1][k]*w.z; w1v.w += h[1][k]*w.w;
                    w2v.x += h[2][k]*w.x; w2v.y += h[2][k]*w.y; w2v.z += h[2][k]*w.z; w2v.w += h[2][k]*w.w;
                    w3.x  += h[3][k]*w.x; w3.y  += h[3][k]*w.y; w3.z  += h[3][k]*w.z; w3.w  += h[3][k]*w.w;
                }
                m0[q].x += xi0*w0.x;  m0[q].y += xi0*w0.y;  m0[q].z += xi0*w0.z;  m0[q].w += xi0*w0.w;
                m1[q].x += xi1*w1v.x; m1[q].y += xi1*w1v.y; m1[q].z += xi1*w1v.z; m1[q].w += xi1*w1v.w;
                m2[q].x += xi2*w2v.x; m2[q].y += xi2*w2v.y; m2[q].z += xi2*w2v.z; m2[q].w += xi2*w2v.w;
                m3[q].x += xi3*w3.x;  m3[q].y += xi3*w3.y;  m3[q].z += xi3*w3.z;  m3[q].w += xi3*w3.w;
            }
        }
    }

    float4* mp0 = (float4*)(msg + (size_t)pb * 16);
    float4* mp1 = (float4*)(msg + (size_t)(pb + 256) * 16);
    float4* mp2 = (float4*)(msg + (size_t)(pb + 512) * 16);
    float4* mp3 = (float4*)(msg + (size_t)(pb + 768) * 16);
#pragma unroll
    for (int q = 0; q < 4; ++q) mp0[q] = m0[q];
#pragma unroll
    for (int q = 0; q < 4; ++q) mp1[q] = m1[q];
#pragma unroll
    for (int q = 0; q < 4; ++q) mp2[q] = m2[q];
#pragma unroll
    for (int q = 0; q < 4; ++q) mp3[q] = m3[q];
}

// ---------------- reduce2: h2 = relu(segsum(msg) + h1@root2 + bias2) ---------
__global__ __launch_bounds__(256) void k_reduce2(
    const float* __restrict__ msg, const int* __restrict__ offs,
    const float* __restrict__ h1, const float* __restrict__ root,
    const float* __restrict__ bias, float* __restrict__ h2)
{
    __shared__ float s_r[512];   // [32][16]
    __shared__ float s_b[16];
    int tid = threadIdx.x;
    for (int i = tid; i < 512; i += 256) s_r[i] = root[i];
    if (tid < 16) s_b[tid] = bias[tid];
    __syncthreads();
    int gid = blockIdx.x * 256 + tid;
    int n = gid >> 2, q = gid & 3;       // 4 float4 columns per node
    int s = offs[n], e = offs[n + 1];
    float4 acc = make_float4(s_b[4*q], s_b[4*q+1], s_b[4*q+2], s_b[4*q+3]);
    const float4* s_r4 = (const float4*)s_r;   // [32][4]
    const float* xp = h1 + (size_t)n * 32;
#pragma unroll
    for (int i = 0; i < 32; ++i) {
        float xi = xp[i];
        float4 w = s_r4[i*4 + q];
        acc.x += xi*w.x; acc.y += xi*w.y; acc.z += xi*w.z; acc.w += xi*w.w;
    }
    for (int p = s; p < e; ++p) {
        float4 mr = ((const float4*)(msg + (size_t)p * 16))[q];
        acc.x += mr.x; acc.y += mr.y; acc.z += mr.z; acc.w += mr.w;
    }
    acc.x = fmaxf(acc.x, 0.f); acc.y = fmaxf(acc.y, 0.f);
    acc.z = fmaxf(acc.z, 0.f); acc.w = fmaxf(acc.w, 0.f);
    ((float4*)(h2 + (size_t)n * 16))[q] = acc;
}

// ---------------- mean pool + concat + head ---------------------------------
__global__ __launch_bounds__(64) void k_head(
    const float* __restrict__ h2, const float* __restrict__ x_att,
    const int* __restrict__ goffs,
    const float* __restrict__ l1w, const float* __restrict__ l1b,
    const float* __restrict__ l2w, const float* __restrict__ l2b,
    float* __restrict__ out)
{
    int g = blockIdx.x;
    int lane = threadIdx.x;
    int s = goffs[g], e = goffs[g + 1];
    __shared__ float v[32];
    __shared__ float hmid[8];
    int f = lane & 15, sub = lane >> 4;
    float acc = 0.f;
    for (int i = s + sub; i < e; i += 4) acc += h2[(size_t)i*16 + f];
    acc += __shfl_xor(acc, 16);
    acc += __shfl_xor(acc, 32);
    float cnt = fmaxf((float)(e - s), 1.0f);
    if (lane < 16) {
        v[lane]      = acc / cnt;
        v[16 + lane] = x_att[g*16 + lane];
    }
    __syncthreads();
    if (lane < 8) {
        float a = l1b[lane];
#pragma unroll
        for (int i = 0; i < 32; ++i) a += v[i] * l1w[i*8 + lane];
        hmid[lane] = a;
    }
    __syncthreads();
    if (lane == 0) {
        float a = l2b[0];
#pragma unroll
        for (int j = 0; j < 8; ++j) a += hmid[j] * l2w[j];
        out[g] = a;
    }
}

extern "C" void kernel_launch(void* const* d_in, const int* in_sizes, int n_in,
                              void* d_out, int out_size, void* d_ws, size_t ws_size,
                              hipStream_t stream) {
    const float* x_p    = (const float*)d_in[0];
    const float* ea_p   = (const float*)d_in[2];
    const int*   ei     = (const int*)d_in[4];
    const int*   batch  = (const int*)d_in[5];
    const float* nn1_w1 = (const float*)d_in[6];
    const float* nn1_b1 = (const float*)d_in[7];
    const float* nn1_w2 = (const float*)d_in[8];
    const float* nn1_b2 = (const float*)d_in[9];
    const float* root1  = (const float*)d_in[10];
    const float* bias1  = (const float*)d_in[11];
    const float* nn2_w1 = (const float*)d_in[12];
    const float* nn2_b1 = (const float*)d_in[13];
    const float* nn2_w2 = (const float*)d_in[14];
    const float* nn2_b2 = (const float*)d_in[15];
    const float* root2  = (const float*)d_in[16];
    const float* bias2  = (const float*)d_in[17];
    const float* gw1    = (const float*)d_in[18];
    const float* gb1    = (const float*)d_in[19];
    const float* gw2    = (const float*)d_in[20];
    const float* gb2    = (const float*)d_in[21];
    const float* l1w    = (const float*)d_in[22];
    const float* l1b    = (const float*)d_in[23];
    const float* l2w    = (const float*)d_in[24];
    const float* l2b    = (const float*)d_in[25];

    // -------- workspace layout (floats/ints), ~48 MB total --------
    float* h1    = (float*)d_ws;                     // NN*32
    float* h2    = h1 + (size_t)NN * 32;             // NN*16
    float* g_all = h2 + (size_t)NN * 16;             // NN
    float* x_att = g_all + NN;                       // NG*16
    int*   goffs = (int*)(x_att + (size_t)NG * 16);  // NG+1 (pad to 2052)
    int*   offs  = goffs + 2052;                     // NN+1 (pad to 65540)
    int*   cnt   = offs + 65540;                     // NN (hist, then cursor)
    int*   bsum  = cnt + NN;                         // 256
    int*   boff  = bsum + 256;                       // 256
    int*   eperm = boff + 256;                       // NE
    float* msg   = (float*)(eperm + NE);             // NE*32 (conv1), reused NE*16 (conv2)

    // -------- attention pool path --------
    k_gate<<<NN/256, 256, 0, stream>>>(x_p, gw1, gb1, gw2, gb2, g_all);
    k_goffsets<<<(NG + 1 + 255)/256, 256, 0, stream>>>(batch, goffs);
    k_attpool<<<NG, 64, 0, stream>>>(x_p, g_all, goffs, x_att);

    // -------- CSR build over dst --------
    hipMemsetAsync(cnt, 0, (size_t)NN * sizeof(int), stream);
    k_hist<<<NE/256, 256, 0, stream>>>(ei, cnt);
    k_scan_blk<<<NN/256, 256, 0, stream>>>(cnt, offs, bsum);
    k_scan_top<<<1, 256, 0, stream>>>(bsum, boff);
    k_scan_add<<<NN/256, 256, 0, stream>>>(offs, boff);
    hipMemsetAsync(cnt, 0, (size_t)NN * sizeof(int), stream);
    k_scatter<<<NE/256, 256, 0, stream>>>(ei, offs, cnt, eperm);

    // -------- conv1 + fused node update --------
    k_conv1<<<NE/1024, 256, 0, stream>>>(x_p, ea_p, ei, eperm,
                                         nn1_w1, nn1_b1, nn1_w2, nn1_b2, msg);
    k_reduce1<<<NN*8/256, 256, 0, stream>>>(msg, offs, x_p, root1, bias1, h1);

    // -------- conv2 + fused node update --------
    k_conv2<<<NE/1024, 256, 0, stream>>>(h1, ea_p, ei, eperm,
                                         nn2_w1, nn2_b1, nn2_w2, nn2_b2, msg);
    k_reduce2<<<NN*4/256, 256, 0, stream>>>(msg, offs, h1, root2, bias2, h2);

    // -------- head --------
    k_head<<<NG, 64, 0, stream>>>(h2, x_att, goffs, l1w, l1b, l2w, l2b, (float*)d_out);
}

// Round 5
// 180.355 us; speedup vs baseline: 3.4692x; 3.4692x over previous
//
#include <hip/hip_runtime.h>

#define NN 65536
#define NE 262144
#define NG 2048

typedef __attribute__((ext_vector_type(16))) float f32x16;
typedef __attribute__((ext_vector_type(4)))  float f32x4;
typedef __attribute__((ext_vector_type(8)))  __bf16 bf16x8;

// pack two fp32 -> dword of two bf16 (truncation); low16 = a, high16 = b
__device__ inline unsigned pack2(float a, float b) {
    return __builtin_amdgcn_perm(__float_as_uint(b), __float_as_uint(a), 0x07060302u);
}
// remainder after bf16-truncation (exact in fp32)
__device__ inline float lof(float p) {
    return p - __uint_as_float(__float_as_uint(p) & 0xffff0000u);
}
__device__ inline bf16x8 asb(uint4 u) { return __builtin_bit_cast(bf16x8, u); }

// ---------------- gate logits ------------------------------------------------
__global__ __launch_bounds__(256) void k_gate(const float* __restrict__ x,
    const float* __restrict__ gw1, const float* __restrict__ gb1,
    const float* __restrict__ gw2, const float* __restrict__ gb2,
    float* __restrict__ g_all)
{
    __shared__ float s_w[256];
    __shared__ float s_b[16];
    __shared__ float s_w2[16];
    __shared__ float s_b2;
    int tid = threadIdx.x;
    s_w[tid & 255] = gw1[tid & 255];
    if (tid < 16) { s_b[tid] = gb1[tid]; s_w2[tid] = gw2[tid]; }
    if (tid == 0) s_b2 = gb2[0];
    __syncthreads();
    int n = blockIdx.x * 256 + tid;
    if (n >= NN) return;
    float xv[16];
    const float4* xp = (const float4*)(x + (size_t)n * 16);
#pragma unroll
    for (int i = 0; i < 4; ++i) {
        float4 t = xp[i];
        xv[4*i] = t.x; xv[4*i+1] = t.y; xv[4*i+2] = t.z; xv[4*i+3] = t.w;
    }
    float g = s_b2;
#pragma unroll
    for (int j = 0; j < 16; ++j) {
        float a = s_b[j];
#pragma unroll
        for (int i = 0; i < 16; ++i) a += xv[i] * s_w[i*16 + j];
        g += fmaxf(a, 0.f) * s_w2[j];
    }
    g_all[n] = g;
}

// ---------------- graph boundary offsets (batch sorted) ----------------------
__global__ void k_goffsets(const int* __restrict__ batch, int* __restrict__ goffs)
{
    int g = blockIdx.x * blockDim.x + threadIdx.x;
    if (g > NG) return;
    int lo = 0, hi = NN;
    while (lo < hi) {
        int mid = (lo + hi) >> 1;
        if (batch[mid] < g) lo = mid + 1; else hi = mid;
    }
    goffs[g] = lo;
}

// ---------------- attention pool over raw x ----------------------------------
__global__ __launch_bounds__(64) void k_attpool(const float* __restrict__ x,
    const float* __restrict__ g_all, const int* __restrict__ goffs,
    float* __restrict__ x_att)
{
    int g = blockIdx.x;
    int lane = threadIdx.x;
    int s = goffs[g], e = goffs[g + 1];
    if (s >= e) {
        if (lane < 16) x_att[g*16 + lane] = 0.f;
        return;
    }
    float m = -1e30f;
    for (int i = s + lane; i < e; i += 64) m = fmaxf(m, g_all[i]);
#pragma unroll
    for (int d = 32; d; d >>= 1) m = fmaxf(m, __shfl_xor(m, d));
    float sum = 0.f;
    for (int i = s + lane; i < e; i += 64) sum += expf(g_all[i] - m);
#pragma unroll
    for (int d = 32; d; d >>= 1) sum += __shfl_xor(sum, d);
    float inv = 1.f / sum;
    int f = lane & 15, sub = lane >> 4;
    float acc = 0.f;
    for (int i = s + sub; i < e; i += 4) {
        float w = expf(g_all[i] - m) * inv;
        acc += w * x[(size_t)i*16 + f];
    }
    acc += __shfl_xor(acc, 16);
    acc += __shfl_xor(acc, 32);
    if (lane < 16) x_att[g*16 + f] = acc;
}

// ---------------- CSR build: histogram / scan / scatter ----------------------
__global__ __launch_bounds__(256) void k_hist(const int* __restrict__ ei, int* __restrict__ cnt)
{
    int e = blockIdx.x * 256 + threadIdx.x;
    if (e >= NE) return;
    atomicAdd(&cnt[ei[NE + e]], 1);
}

__global__ __launch_bounds__(256) void k_scan_blk(const int* __restrict__ cnt,
    int* __restrict__ offs, int* __restrict__ bsum)
{
    __shared__ int s[256];
    int t = threadIdx.x, b = blockIdx.x;
    int v = cnt[b*256 + t];
    s[t] = v;
    __syncthreads();
#pragma unroll
    for (int d = 1; d < 256; d <<= 1) {
        int add = (t >= d) ? s[t - d] : 0;
        __syncthreads();
        s[t] += add;
        __syncthreads();
    }
    offs[b*256 + t] = s[t] - v;
    if (t == 255) bsum[b] = s[255];
}

__global__ __launch_bounds__(256) void k_scan_top(const int* __restrict__ bsum,
    int* __restrict__ boff)
{
    __shared__ int s[256];
    int t = threadIdx.x;
    int v = bsum[t];
    s[t] = v;
    __syncthreads();
#pragma unroll
    for (int d = 1; d < 256; d <<= 1) {
        int add = (t >= d) ? s[t - d] : 0;
        __syncthreads();
        s[t] += add;
        __syncthreads();
    }
    boff[t] = s[t] - v;
}

__global__ __launch_bounds__(256) void k_scan_add(int* __restrict__ offs,
    const int* __restrict__ boff)
{
    int i = blockIdx.x * 256 + threadIdx.x;
    if (i == 0) offs[NN] = NE;
    if (i >= NN) return;
    offs[i] += boff[i >> 8];
}

__global__ __launch_bounds__(256) void k_scatter(const int* __restrict__ ei,
    const int* __restrict__ offs, int* __restrict__ cur, int* __restrict__ eperm)
{
    int e = blockIdx.x * 256 + threadIdx.x;
    if (e >= NE) return;
    int d = ei[NE + e];
    int pos = offs[d] + atomicAdd(&cur[d], 1);
    eperm[pos] = e;
}

// ---------------- W-fragment prep (split-bf16, MFMA B-operand layout) --------
// c(g,j) = g*8+j within a K-step; identical convention used when building A.
__global__ void k_prep(const float* __restrict__ w2a, const float* __restrict__ b2a,
                       const float* __restrict__ w2b, const float* __restrict__ b2c,
                       unsigned* __restrict__ f1, unsigned* __restrict__ f2)
{
    int l = threadIdx.x;   // 64 lanes
    {   // conv1: 32x32x16, N=32: n = l&31, g = l>>5
        int n = l & 31, g = l >> 5;
        for (int s = 0; s < 17; ++s) {
            for (int d = 0; d < 4; ++d) {
                int j0 = 2*d;
                int c0 = (g*8 + j0)*32 + n;
                int c1 = c0 + 32;
                float a = (s < 16) ? w2a[s*512 + c0] : b2a[c0];
                float b = (s < 16) ? w2a[s*512 + c1] : b2a[c1];
                f1[((s*2+0)*64 + l)*4 + d] = pack2(a, b);
                f1[((s*2+1)*64 + l)*4 + d] = pack2(lof(a), lof(b));
            }
        }
    }
    {   // conv2: 16x16x32, N=16: n = l&15, g = l>>4
        int n = l & 15, g = l >> 4;
        for (int s = 0; s < 17; ++s) {
            for (int d = 0; d < 4; ++d) {
                int j0 = 2*d;
                int c0 = (g*8 + j0)*16 + n;
                int c1 = c0 + 16;
                float a = (s < 16) ? w2b[s*512 + c0] : b2c[c0];
                float b = (s < 16) ? w2b[s*512 + c1] : b2c[c1];
                f2[((s*2+0)*64 + l)*4 + d] = pack2(a, b);
                f2[((s*2+1)*64 + l)*4 + d] = pack2(lof(a), lof(b));
            }
        }
    }
}

// ---------------- conv1: NNConv(16->32) via MFMA 32x32x16 --------------------
// wave tile = 32 edges; K = 17 steps (k=0..15 of h, step16 = bias with h=1).
__global__ __launch_bounds__(256) void k_conv1(
    const float* __restrict__ x, const float* __restrict__ ea,
    const int* __restrict__ ei, const int* __restrict__ eperm,
    const float* __restrict__ w1, const float* __restrict__ b1,
    const unsigned* __restrict__ bfrag, float* __restrict__ msg)
{
    __shared__ uint4 lds[17*2*64];
    const int tid = threadIdx.x;
    for (int i = tid; i < 17*2*64; i += 256) lds[i] = ((const uint4*)bfrag)[i];
    __syncthreads();
    const int lane = tid & 63;
    const int wid  = tid >> 6;
    const int m    = lane & 31;     // A row (edge in tile); for D: col = out channel
    const int g    = lane >> 5;     // k-group

    for (int tile = blockIdx.x*4 + wid; tile < NE/32; tile += 4096) {
        const int p   = tile*32 + m;
        const int e   = eperm[p];
        const int src = ei[e];

        float xs[8];
        {
            const float4* xp = (const float4*)(x + (size_t)src*16 + g*8);
            float4 aa = xp[0], bb = xp[1];
            xs[0]=aa.x; xs[1]=aa.y; xs[2]=aa.z; xs[3]=aa.w;
            xs[4]=bb.x; xs[5]=bb.y; xs[6]=bb.z; xs[7]=bb.w;
        }
        float h[17];
        {
            const float2 e01 = *(const float2*)(ea + (size_t)e*6);
            const float2 e23 = *(const float2*)(ea + (size_t)e*6 + 2);
            const float2 e45 = *(const float2*)(ea + (size_t)e*6 + 4);
            const float a0=e01.x, a1=e01.y, a2=e23.x, a3=e23.y, a4=e45.x, a5=e45.y;
#pragma unroll
            for (int j = 0; j < 16; ++j) {
                float c = b1[j];
                c += a0*w1[0*16+j]; c += a1*w1[1*16+j]; c += a2*w1[2*16+j];
                c += a3*w1[3*16+j]; c += a4*w1[4*16+j]; c += a5*w1[5*16+j];
                h[j] = fmaxf(c, 0.f);
            }
            h[16] = 1.f;
        }

        f32x16 acc = {};
#pragma unroll
        for (int s = 0; s < 17; ++s) {
            const float hs = h[s];
            float p0 = hs*xs[0], p1 = hs*xs[1], p2 = hs*xs[2], p3 = hs*xs[3];
            float p4 = hs*xs[4], p5 = hs*xs[5], p6 = hs*xs[6], p7 = hs*xs[7];
            uint4 uh = { pack2(p0,p1), pack2(p2,p3), pack2(p4,p5), pack2(p6,p7) };
            uint4 ul = { pack2(lof(p0),lof(p1)), pack2(lof(p2),lof(p3)),
                         pack2(lof(p4),lof(p5)), pack2(lof(p6),lof(p7)) };
            uint4 wh = lds[(s*2+0)*64 + lane];
            uint4 wl = lds[(s*2+1)*64 + lane];
            acc = __builtin_amdgcn_mfma_f32_32x32x16_bf16(asb(uh), asb(wh), acc, 0, 0, 0);
            acc = __builtin_amdgcn_mfma_f32_32x32x16_bf16(asb(uh), asb(wl), acc, 0, 0, 0);
            acc = __builtin_amdgcn_mfma_f32_32x32x16_bf16(asb(ul), asb(wh), acc, 0, 0, 0);
        }

        float* mbase = msg + (size_t)tile*32*32;
        const int rb = g*4;
#pragma unroll
        for (int r = 0; r < 16; ++r) {
            int mr = (r&3) + 8*(r>>2) + rb;          // D row = edge-in-tile
            mbase[(size_t)mr*32 + m] = acc[r];       // D col (lane&31) = out channel
        }
    }
}

// ---------------- conv2: NNConv(32->16) via MFMA 16x16x32 --------------------
__global__ __launch_bounds__(256) void k_conv2(
    const float* __restrict__ x, const float* __restrict__ ea,
    const int* __restrict__ ei, const int* __restrict__ eperm,
    const float* __restrict__ w1, const float* __restrict__ b1,
    const unsigned* __restrict__ bfrag, float* __restrict__ msg)
{
    __shared__ uint4 lds[17*2*64];
    const int tid = threadIdx.x;
    for (int i = tid; i < 17*2*64; i += 256) lds[i] = ((const uint4*)bfrag)[i];
    __syncthreads();
    const int lane = tid & 63;
    const int wid  = tid >> 6;
    const int m    = lane & 15;     // edge in tile; for D: col = out channel
    const int g    = lane >> 4;     // k-group (0..3)

    for (int tile = blockIdx.x*4 + wid; tile < NE/16; tile += 4096) {
        const int p   = tile*16 + m;
        const int e   = eperm[p];
        const int src = ei[e];

        float xs[8];
        {
            const float4* xp = (const float4*)(x + (size_t)src*32 + g*8);
            float4 aa = xp[0], bb = xp[1];
            xs[0]=aa.x; xs[1]=aa.y; xs[2]=aa.z; xs[3]=aa.w;
            xs[4]=bb.x; xs[5]=bb.y; xs[6]=bb.z; xs[7]=bb.w;
        }
        float h[17];
        {
            const float2 e01 = *(const float2*)(ea + (size_t)e*6);
            const float2 e23 = *(const float2*)(ea + (size_t)e*6 + 2);
            const float2 e45 = *(const float2*)(ea + (size_t)e*6 + 4);
            const float a0=e01.x, a1=e01.y, a2=e23.x, a3=e23.y, a4=e45.x, a5=e45.y;
#pragma unroll
            for (int j = 0; j < 16; ++j) {
                float c = b1[j];
                c += a0*w1[0*16+j]; c += a1*w1[1*16+j]; c += a2*w1[2*16+j];
                c += a3*w1[3*16+j]; c += a4*w1[4*16+j]; c += a5*w1[5*16+j];
                h[j] = fmaxf(c, 0.f);
            }
            h[16] = 1.f;
        }

        f32x4 acc = {};
#pragma unroll
        for (int s = 0; s < 17; ++s) {
            const float hs = h[s];
            float p0 = hs*xs[0], p1 = hs*xs[1], p2 = hs*xs[2], p3 = hs*xs[3];
            float p4 = hs*xs[4], p5 = hs*xs[5], p6 = hs*xs[6], p7 = hs*xs[7];
            uint4 uh = { pack2(p0,p1), pack2(p2,p3), pack2(p4,p5), pack2(p6,p7) };
            uint4 ul = { pack2(lof(p0),lof(p1)), pack2(lof(p2),lof(p3)),
                         pack2(lof(p4),lof(p5)), pack2(lof(p6),lof(p7)) };
            uint4 wh = lds[(s*2+0)*64 + lane];
            uint4 wl = lds[(s*2+1)*64 + lane];
            acc = __builtin_amdgcn_mfma_f32_16x16x32_bf16(asb(uh), asb(wh), acc, 0, 0, 0);
            acc = __builtin_amdgcn_mfma_f32_16x16x32_bf16(asb(uh), asb(wl), acc, 0, 0, 0);
            acc = __builtin_amdgcn_mfma_f32_16x16x32_bf16(asb(ul), asb(wh), acc, 0, 0, 0);
        }

        float* mbase = msg + (size_t)tile*16*16;
#pragma unroll
        for (int r = 0; r < 4; ++r) {
            int mr = g*4 + r;                        // D row = edge-in-tile
            mbase[(size_t)mr*16 + m] = acc[r];       // D col (lane&15) = out channel
        }
    }
}

// ---------------- reduce1: h1 = relu(segsum(msg) + x@root1 + bias1) ----------
__global__ __launch_bounds__(256) void k_reduce1(
    const float* __restrict__ msg, const int* __restrict__ offs,
    const float* __restrict__ x, const float* __restrict__ root,
    const float* __restrict__ bias, float* __restrict__ h1)
{
    __shared__ float s_r[512];   // [16][32]
    __shared__ float s_b[32];
    int tid = threadIdx.x;
    for (int i = tid; i < 512; i += 256) s_r[i] = root[i];
    if (tid < 32) s_b[tid] = bias[tid];
    __syncthreads();
    int gid = blockIdx.x * 256 + tid;
    int n = gid >> 3, q = gid & 7;
    int s = offs[n], e = offs[n + 1];
    float4 acc = make_float4(s_b[4*q], s_b[4*q+1], s_b[4*q+2], s_b[4*q+3]);
    const float4* s_r4 = (const float4*)s_r;
    const float* xp = x + (size_t)n * 16;
#pragma unroll
    for (int i = 0; i < 16; ++i) {
        float xi = xp[i];
        float4 w = s_r4[i*8 + q];
        acc.x += xi*w.x; acc.y += xi*w.y; acc.z += xi*w.z; acc.w += xi*w.w;
    }
    for (int p = s; p < e; ++p) {
        float4 mr = ((const float4*)(msg + (size_t)p * 32))[q];
        acc.x += mr.x; acc.y += mr.y; acc.z += mr.z; acc.w += mr.w;
    }
    acc.x = fmaxf(acc.x, 0.f); acc.y = fmaxf(acc.y, 0.f);
    acc.z = fmaxf(acc.z, 0.f); acc.w = fmaxf(acc.w, 0.f);
    ((float4*)(h1 + (size_t)n * 32))[q] = acc;
}

// ---------------- reduce2: h2 = relu(segsum(msg) + h1@root2 + bias2) ---------
__global__ __launch_bounds__(256) void k_reduce2(
    const float* __restrict__ msg, const int* __restrict__ offs,
    const float* __restrict__ h1, const float* __restrict__ root,
    const float* __restrict__ bias, float* __restrict__ h2)
{
    __shared__ float s_r[512];   // [32][16]
    __shared__ float s_b[16];
    int tid = threadIdx.x;
    for (int i = tid; i < 512; i += 256) s_r[i] = root[i];
    if (tid < 16) s_b[tid] = bias[tid];
    __syncthreads();
    int gid = blockIdx.x * 256 + tid;
    int n = gid >> 2, q = gid & 3;
    int s = offs[n], e = offs[n + 1];
    float4 acc = make_float4(s_b[4*q], s_b[4*q+1], s_b[4*q+2], s_b[4*q+3]);
    const float4* s_r4 = (const float4*)s_r;
    const float* xp = h1 + (size_t)n * 32;
#pragma unroll
    for (int i = 0; i < 32; ++i) {
        float xi = xp[i];
        float4 w = s_r4[i*4 + q];
        acc.x += xi*w.x; acc.y += xi*w.y; acc.z += xi*w.z; acc.w += xi*w.w;
    }
    for (int p = s; p < e; ++p) {
        float4 mr = ((const float4*)(msg + (size_t)p * 16))[q];
        acc.x += mr.x; acc.y += mr.y; acc.z += mr.z; acc.w += mr.w;
    }
    acc.x = fmaxf(acc.x, 0.f); acc.y = fmaxf(acc.y, 0.f);
    acc.z = fmaxf(acc.z, 0.f); acc.w = fmaxf(acc.w, 0.f);
    ((float4*)(h2 + (size_t)n * 16))[q] = acc;
}

// ---------------- mean pool + concat + head ----------------------------------
__global__ __launch_bounds__(64) void k_head(
    const float* __restrict__ h2, const float* __restrict__ x_att,
    const int* __restrict__ goffs,
    const float* __restrict__ l1w, const float* __restrict__ l1b,
    const float* __restrict__ l2w, const float* __restrict__ l2b,
    float* __restrict__ out)
{
    int g = blockIdx.x;
    int lane = threadIdx.x;
    int s = goffs[g], e = goffs[g + 1];
    __shared__ float v[32];
    __shared__ float hmid[8];
    int f = lane & 15, sub = lane >> 4;
    float acc = 0.f;
    for (int i = s + sub; i < e; i += 4) acc += h2[(size_t)i*16 + f];
    acc += __shfl_xor(acc, 16);
    acc += __shfl_xor(acc, 32);
    float cnt = fmaxf((float)(e - s), 1.0f);
    if (lane < 16) {
        v[lane]      = acc / cnt;
        v[16 + lane] = x_att[g*16 + lane];
    }
    __syncthreads();
    if (lane < 8) {
        float a = l1b[lane];
#pragma unroll
        for (int i = 0; i < 32; ++i) a += v[i] * l1w[i*8 + lane];
        hmid[lane] = a;
    }
    __syncthreads();
    if (lane == 0) {
        float a = l2b[0];
#pragma unroll
        for (int j = 0; j < 8; ++j) a += hmid[j] * l2w[j];
        out[g] = a;
    }
}

extern "C" void kernel_launch(void* const* d_in, const int* in_sizes, int n_in,
                              void* d_out, int out_size, void* d_ws, size_t ws_size,
                              hipStream_t stream) {
    const float* x_p    = (const float*)d_in[0];
    const float* ea_p   = (const float*)d_in[2];
    const int*   ei     = (const int*)d_in[4];
    const int*   batch  = (const int*)d_in[5];
    const float* nn1_w1 = (const float*)d_in[6];
    const float* nn1_b1 = (const float*)d_in[7];
    const float* nn1_w2 = (const float*)d_in[8];
    const float* nn1_b2 = (const float*)d_in[9];
    const float* root1  = (const float*)d_in[10];
    const float* bias1  = (const float*)d_in[11];
    const float* nn2_w1 = (const float*)d_in[12];
    const float* nn2_b1 = (const float*)d_in[13];
    const float* nn2_w2 = (const float*)d_in[14];
    const float* nn2_b2 = (const float*)d_in[15];
    const float* root2  = (const float*)d_in[16];
    const float* bias2  = (const float*)d_in[17];
    const float* gw1    = (const float*)d_in[18];
    const float* gb1    = (const float*)d_in[19];
    const float* gw2    = (const float*)d_in[20];
    const float* gb2    = (const float*)d_in[21];
    const float* l1w    = (const float*)d_in[22];
    const float* l1b    = (const float*)d_in[23];
    const float* l2w    = (const float*)d_in[24];
    const float* l2b    = (const float*)d_in[25];

    // -------- workspace layout --------
    float*    h1     = (float*)d_ws;                     // NN*32
    float*    h2     = h1 + (size_t)NN * 32;             // NN*16
    float*    g_all  = h2 + (size_t)NN * 16;             // NN
    float*    x_att  = g_all + NN;                       // NG*16
    int*      goffs  = (int*)(x_att + (size_t)NG * 16);  // 2052
    int*      offs   = goffs + 2052;                     // 65540
    int*      cnt    = offs + 65540;                     // NN
    int*      bsum   = cnt + NN;                         // 256
    int*      boff   = bsum + 256;                       // 256
    int*      eperm  = boff + 256;                       // NE
    unsigned* bfrag1 = (unsigned*)(eperm + NE);          // 17*2*64*4 = 8704
    unsigned* bfrag2 = bfrag1 + 8704;                    // 8704
    float*    msg    = (float*)(bfrag2 + 8704);          // NE*32 (conv1) / NE*16 (conv2)

    // -------- attention pool path --------
    k_gate<<<NN/256, 256, 0, stream>>>(x_p, gw1, gb1, gw2, gb2, g_all);
    k_goffsets<<<(NG + 1 + 255)/256, 256, 0, stream>>>(batch, goffs);
    k_attpool<<<NG, 64, 0, stream>>>(x_p, g_all, goffs, x_att);

    // -------- CSR build over dst --------
    hipMemsetAsync(cnt, 0, (size_t)NN * sizeof(int), stream);
    k_hist<<<NE/256, 256, 0, stream>>>(ei, cnt);
    k_scan_blk<<<NN/256, 256, 0, stream>>>(cnt, offs, bsum);
    k_scan_top<<<1, 256, 0, stream>>>(bsum, boff);
    k_scan_add<<<NN/256, 256, 0, stream>>>(offs, boff);
    hipMemsetAsync(cnt, 0, (size_t)NN * sizeof(int), stream);
    k_scatter<<<NE/256, 256, 0, stream>>>(ei, offs, cnt, eperm);

    // -------- W fragment prep --------
    k_prep<<<1, 64, 0, stream>>>(nn1_w2, nn1_b2, nn2_w2, nn2_b2, bfrag1, bfrag2);

    // -------- conv1 + fused node update --------
    k_conv1<<<1024, 256, 0, stream>>>(x_p, ea_p, ei, eperm, nn1_w1, nn1_b1, bfrag1, msg);
    k_reduce1<<<NN*8/256, 256, 0, stream>>>(msg, offs, x_p, root1, bias1, h1);

    // -------- conv2 + fused node update --------
    k_conv2<<<1024, 256, 0, stream>>>(h1, ea_p, ei, eperm, nn2_w1, nn2_b1, bfrag2, msg);
    k_reduce2<<<NN*4/256, 256, 0, stream>>>(msg, offs, h1, root2, bias2, h2);

    // -------- head --------
    k_head<<<NG, 64, 0, stream>>>(h2, x_att, goffs, l1w, l1b, l2w, l2b, (float*)d_out);
}

// Round 6
// 137.166 us; speedup vs baseline: 4.5616x; 1.3149x over previous
//
#include <hip/hip_runtime.h>

#define NN 65536
#define NE 262144
#define NG 2048

typedef __attribute__((ext_vector_type(16))) float f32x16;
typedef __attribute__((ext_vector_type(4)))  float f32x4;
typedef __attribute__((ext_vector_type(8)))  __bf16 bf16x8;

// pack two fp32 -> dword of two bf16 (truncation); low16 = a, high16 = b
__device__ inline unsigned pack2(float a, float b) {
    return __builtin_amdgcn_perm(__float_as_uint(b), __float_as_uint(a), 0x07060302u);
}
// remainder after bf16-truncation (exact in fp32)
__device__ inline float lof(float p) {
    return p - __uint_as_float(__float_as_uint(p) & 0xffff0000u);
}
__device__ inline bf16x8 asb(uint4 u) { return __builtin_bit_cast(bf16x8, u); }

// ---------------- gate logits ------------------------------------------------
__global__ __launch_bounds__(256) void k_gate(const float* __restrict__ x,
    const float* __restrict__ gw1, const float* __restrict__ gb1,
    const float* __restrict__ gw2, const float* __restrict__ gb2,
    float* __restrict__ g_all)
{
    __shared__ float s_w[256];
    __shared__ float s_b[16];
    __shared__ float s_w2[16];
    __shared__ float s_b2;
    int tid = threadIdx.x;
    s_w[tid & 255] = gw1[tid & 255];
    if (tid < 16) { s_b[tid] = gb1[tid]; s_w2[tid] = gw2[tid]; }
    if (tid == 0) s_b2 = gb2[0];
    __syncthreads();
    int n = blockIdx.x * 256 + tid;
    if (n >= NN) return;
    float xv[16];
    const float4* xp = (const float4*)(x + (size_t)n * 16);
#pragma unroll
    for (int i = 0; i < 4; ++i) {
        float4 t = xp[i];
        xv[4*i] = t.x; xv[4*i+1] = t.y; xv[4*i+2] = t.z; xv[4*i+3] = t.w;
    }
    float g = s_b2;
#pragma unroll
    for (int j = 0; j < 16; ++j) {
        float a = s_b[j];
#pragma unroll
        for (int i = 0; i < 16; ++i) a += xv[i] * s_w[i*16 + j];
        g += fmaxf(a, 0.f) * s_w2[j];
    }
    g_all[n] = g;
}

// ---------------- graph boundary offsets (batch sorted) ----------------------
__global__ void k_goffsets(const int* __restrict__ batch, int* __restrict__ goffs)
{
    int g = blockIdx.x * blockDim.x + threadIdx.x;
    if (g > NG) return;
    int lo = 0, hi = NN;
    while (lo < hi) {
        int mid = (lo + hi) >> 1;
        if (batch[mid] < g) lo = mid + 1; else hi = mid;
    }
    goffs[g] = lo;
}

// ---------------- attention pool over raw x ----------------------------------
__global__ __launch_bounds__(64) void k_attpool(const float* __restrict__ x,
    const float* __restrict__ g_all, const int* __restrict__ goffs,
    float* __restrict__ x_att)
{
    int g = blockIdx.x;
    int lane = threadIdx.x;
    int s = goffs[g], e = goffs[g + 1];
    if (s >= e) {
        if (lane < 16) x_att[g*16 + lane] = 0.f;
        return;
    }
    float m = -1e30f;
    for (int i = s + lane; i < e; i += 64) m = fmaxf(m, g_all[i]);
#pragma unroll
    for (int d = 32; d; d >>= 1) m = fmaxf(m, __shfl_xor(m, d));
    float sum = 0.f;
    for (int i = s + lane; i < e; i += 64) sum += expf(g_all[i] - m);
#pragma unroll
    for (int d = 32; d; d >>= 1) sum += __shfl_xor(sum, d);
    float inv = 1.f / sum;
    int f = lane & 15, sub = lane >> 4;
    float acc = 0.f;
    for (int i = s + sub; i < e; i += 4) {
        float w = expf(g_all[i] - m) * inv;
        acc += w * x[(size_t)i*16 + f];
    }
    acc += __shfl_xor(acc, 16);
    acc += __shfl_xor(acc, 32);
    if (lane < 16) x_att[g*16 + f] = acc;
}

// ---------------- CSR build: histogram / scan / scatter ----------------------
__global__ __launch_bounds__(256) void k_hist(const int* __restrict__ ei, int* __restrict__ cnt)
{
    int e = blockIdx.x * 256 + threadIdx.x;
    if (e >= NE) return;
    atomicAdd(&cnt[ei[NE + e]], 1);
}

__global__ __launch_bounds__(256) void k_scan_blk(const int* __restrict__ cnt,
    int* __restrict__ offs, int* __restrict__ bsum)
{
    __shared__ int s[256];
    int t = threadIdx.x, b = blockIdx.x;
    int v = cnt[b*256 + t];
    s[t] = v;
    __syncthreads();
#pragma unroll
    for (int d = 1; d < 256; d <<= 1) {
        int add = (t >= d) ? s[t - d] : 0;
        __syncthreads();
        s[t] += add;
        __syncthreads();
    }
    offs[b*256 + t] = s[t] - v;
    if (t == 255) bsum[b] = s[255];
}

__global__ __launch_bounds__(256) void k_scan_top(const int* __restrict__ bsum,
    int* __restrict__ boff)
{
    __shared__ int s[256];
    int t = threadIdx.x;
    int v = bsum[t];
    s[t] = v;
    __syncthreads();
#pragma unroll
    for (int d = 1; d < 256; d <<= 1) {
        int add = (t >= d) ? s[t - d] : 0;
        __syncthreads();
        s[t] += add;
        __syncthreads();
    }
    boff[t] = s[t] - v;
}

__global__ __launch_bounds__(256) void k_scan_add(int* __restrict__ offs,
    const int* __restrict__ boff)
{
    int i = blockIdx.x * 256 + threadIdx.x;
    if (i == 0) offs[NN] = NE;
    if (i >= NN) return;
    offs[i] += boff[i >> 8];
}

__global__ __launch_bounds__(256) void k_scatter(const int* __restrict__ ei,
    const int* __restrict__ offs, int* __restrict__ cur, int* __restrict__ eperm)
{
    int e = blockIdx.x * 256 + threadIdx.x;
    if (e >= NE) return;
    int d = ei[NE + e];
    int pos = offs[d] + atomicAdd(&cur[d], 1);
    eperm[pos] = e;
}

// ---------------- W-fragment prep (split-bf16, MFMA B-operand layout) --------
// One thread per output dword. r = s*512 + t*256 + l*4 + d.
__global__ __launch_bounds__(256) void k_prep(
    const float* __restrict__ w2a, const float* __restrict__ b2a,
    const float* __restrict__ w2b, const float* __restrict__ b2c,
    unsigned* __restrict__ f1, unsigned* __restrict__ f2)
{
    int tg = blockIdx.x * 256 + threadIdx.x;   // 0 .. 17407
    if (tg >= 17408) return;
    int c = tg / 8704;
    int r = tg - c * 8704;
    int d = r & 3;
    int l = (r >> 2) & 63;
    int t = (r >> 8) & 1;
    int s = r >> 9;
    if (c == 0) {   // conv1: 32x32x16, N=32
        int n = l & 31, g = l >> 5;
        int j0 = 2*d;
        int c0 = (g*8 + j0)*32 + n;
        int c1 = c0 + 32;
        float a = (s < 16) ? w2a[s*512 + c0] : b2a[c0];
        float b = (s < 16) ? w2a[s*512 + c1] : b2a[c1];
        f1[r] = t ? pack2(lof(a), lof(b)) : pack2(a, b);
    } else {        // conv2: 16x16x32, N=16
        int n = l & 15, g = l >> 4;
        int j0 = 2*d;
        int c0 = (g*8 + j0)*16 + n;
        int c1 = c0 + 16;
        float a = (s < 16) ? w2b[s*512 + c0] : b2c[c0];
        float b = (s < 16) ? w2b[s*512 + c1] : b2c[c1];
        f2[r] = t ? pack2(lof(a), lof(b)) : pack2(a, b);
    }
}

// ---------------- conv1: NNConv(16->32) via MFMA 32x32x16 --------------------
// 1 tile (32 edges) per wave; B-fragments read lane-indexed from global
// (34.8 KB table, L1-resident). No LDS.
__global__ __launch_bounds__(256) void k_conv1(
    const float* __restrict__ x, const float* __restrict__ ea,
    const int* __restrict__ ei, const int* __restrict__ eperm,
    const float* __restrict__ w1, const float* __restrict__ b1,
    const unsigned* __restrict__ bfrag, float* __restrict__ msg)
{
    const int tid  = threadIdx.x;
    const int lane = tid & 63;
    const int wid  = tid >> 6;
    const int m    = lane & 31;     // edge in tile; for D: col = out channel
    const int g    = lane >> 5;     // k-group
    const uint4* bf4 = (const uint4*)bfrag;

    const int tile = blockIdx.x*4 + wid;
    const int p    = tile*32 + m;
    const int e    = eperm[p];
    const int src  = ei[e];

    float xs[8];
    {
        const float4* xp = (const float4*)(x + (size_t)src*16 + g*8);
        float4 aa = xp[0], bb = xp[1];
        xs[0]=aa.x; xs[1]=aa.y; xs[2]=aa.z; xs[3]=aa.w;
        xs[4]=bb.x; xs[5]=bb.y; xs[6]=bb.z; xs[7]=bb.w;
    }
    float h[17];
    {
        const float2 e01 = *(const float2*)(ea + (size_t)e*6);
        const float2 e23 = *(const float2*)(ea + (size_t)e*6 + 2);
        const float2 e45 = *(const float2*)(ea + (size_t)e*6 + 4);
        const float a0=e01.x, a1=e01.y, a2=e23.x, a3=e23.y, a4=e45.x, a5=e45.y;
#pragma unroll
        for (int j = 0; j < 16; ++j) {
            float c = b1[j];
            c += a0*w1[0*16+j]; c += a1*w1[1*16+j]; c += a2*w1[2*16+j];
            c += a3*w1[3*16+j]; c += a4*w1[4*16+j]; c += a5*w1[5*16+j];
            h[j] = fmaxf(c, 0.f);
        }
        h[16] = 1.f;
    }

    f32x16 acc = {};
#pragma unroll
    for (int s = 0; s < 17; ++s) {
        const float hs = h[s];
        float p0 = hs*xs[0], p1 = hs*xs[1], p2 = hs*xs[2], p3 = hs*xs[3];
        float p4 = hs*xs[4], p5 = hs*xs[5], p6 = hs*xs[6], p7 = hs*xs[7];
        uint4 uh = { pack2(p0,p1), pack2(p2,p3), pack2(p4,p5), pack2(p6,p7) };
        uint4 ul = { pack2(lof(p0),lof(p1)), pack2(lof(p2),lof(p3)),
                     pack2(lof(p4),lof(p5)), pack2(lof(p6),lof(p7)) };
        uint4 wh = bf4[(s*2+0)*64 + lane];
        uint4 wl = bf4[(s*2+1)*64 + lane];
        acc = __builtin_amdgcn_mfma_f32_32x32x16_bf16(asb(uh), asb(wh), acc, 0, 0, 0);
        acc = __builtin_amdgcn_mfma_f32_32x32x16_bf16(asb(uh), asb(wl), acc, 0, 0, 0);
        acc = __builtin_amdgcn_mfma_f32_32x32x16_bf16(asb(ul), asb(wh), acc, 0, 0, 0);
    }

    float* mbase = msg + (size_t)tile*32*32;
    const int rb = g*4;
#pragma unroll
    for (int r = 0; r < 16; ++r) {
        int mr = (r&3) + 8*(r>>2) + rb;          // D row = edge-in-tile
        mbase[(size_t)mr*32 + m] = acc[r];       // D col (lane&31) = out channel
    }
}

// ---------------- conv2: NNConv(32->16) via MFMA 16x16x32 --------------------
__global__ __launch_bounds__(256) void k_conv2(
    const float* __restrict__ x, const float* __restrict__ ea,
    const int* __restrict__ ei, const int* __restrict__ eperm,
    const float* __restrict__ w1, const float* __restrict__ b1,
    const unsigned* __restrict__ bfrag, float* __restrict__ msg)
{
    const int tid  = threadIdx.x;
    const int lane = tid & 63;
    const int wid  = tid >> 6;
    const int m    = lane & 15;     // edge in tile; for D: col = out channel
    const int g    = lane >> 4;     // k-group (0..3)
    const uint4* bf4 = (const uint4*)bfrag;

    const int tile = blockIdx.x*4 + wid;
    const int p    = tile*16 + m;
    const int e    = eperm[p];
    const int src  = ei[e];

    float xs[8];
    {
        const float4* xp = (const float4*)(x + (size_t)src*32 + g*8);
        float4 aa = xp[0], bb = xp[1];
        xs[0]=aa.x; xs[1]=aa.y; xs[2]=aa.z; xs[3]=aa.w;
        xs[4]=bb.x; xs[5]=bb.y; xs[6]=bb.z; xs[7]=bb.w;
    }
    float h[17];
    {
        const float2 e01 = *(const float2*)(ea + (size_t)e*6);
        const float2 e23 = *(const float2*)(ea + (size_t)e*6 + 2);
        const float2 e45 = *(const float2*)(ea + (size_t)e*6 + 4);
        const float a0=e01.x, a1=e01.y, a2=e23.x, a3=e23.y, a4=e45.x, a5=e45.y;
#pragma unroll
        for (int j = 0; j < 16; ++j) {
            float c = b1[j];
            c += a0*w1[0*16+j]; c += a1*w1[1*16+j]; c += a2*w1[2*16+j];
            c += a3*w1[3*16+j]; c += a4*w1[4*16+j]; c += a5*w1[5*16+j];
            h[j] = fmaxf(c, 0.f);
        }
        h[16] = 1.f;
    }

    f32x4 acc = {};
#pragma unroll
    for (int s = 0; s < 17; ++s) {
        const float hs = h[s];
        float p0 = hs*xs[0], p1 = hs*xs[1], p2 = hs*xs[2], p3 = hs*xs[3];
        float p4 = hs*xs[4], p5 = hs*xs[5], p6 = hs*xs[6], p7 = hs*xs[7];
        uint4 uh = { pack2(p0,p1), pack2(p2,p3), pack2(p4,p5), pack2(p6,p7) };
        uint4 ul = { pack2(lof(p0),lof(p1)), pack2(lof(p2),lof(p3)),
                     pack2(lof(p4),lof(p5)), pack2(lof(p6),lof(p7)) };
        uint4 wh = bf4[(s*2+0)*64 + lane];
        uint4 wl = bf4[(s*2+1)*64 + lane];
        acc = __builtin_amdgcn_mfma_f32_16x16x32_bf16(asb(uh), asb(wh), acc, 0, 0, 0);
        acc = __builtin_amdgcn_mfma_f32_16x16x32_bf16(asb(uh), asb(wl), acc, 0, 0, 0);
        acc = __builtin_amdgcn_mfma_f32_16x16x32_bf16(asb(ul), asb(wh), acc, 0, 0, 0);
    }

    float* mbase = msg + (size_t)tile*16*16;
#pragma unroll
    for (int r = 0; r < 4; ++r) {
        int mr = g*4 + r;                        // D row = edge-in-tile
        mbase[(size_t)mr*16 + m] = acc[r];       // D col (lane&15) = out channel
    }
}

// ---------------- reduce1: h1 = relu(segsum(msg) + x@root1 + bias1) ----------
__global__ __launch_bounds__(256) void k_reduce1(
    const float* __restrict__ msg, const int* __restrict__ offs,
    const float* __restrict__ x, const float* __restrict__ root,
    const float* __restrict__ bias, float* __restrict__ h1)
{
    __shared__ float s_r[512];   // [16][32]
    __shared__ float s_b[32];
    int tid = threadIdx.x;
    for (int i = tid; i < 512; i += 256) s_r[i] = root[i];
    if (tid < 32) s_b[tid] = bias[tid];
    __syncthreads();
    int gid = blockIdx.x * 256 + tid;
    int n = gid >> 3, q = gid & 7;
    int s = offs[n], e = offs[n + 1];
    float4 acc = make_float4(s_b[4*q], s_b[4*q+1], s_b[4*q+2], s_b[4*q+3]);
    const float4* s_r4 = (const float4*)s_r;
    const float* xp = x + (size_t)n * 16;
#pragma unroll
    for (int i = 0; i < 16; ++i) {
        float xi = xp[i];
        float4 w = s_r4[i*8 + q];
        acc.x += xi*w.x; acc.y += xi*w.y; acc.z += xi*w.z; acc.w += xi*w.w;
    }
    for (int p = s; p < e; ++p) {
        float4 mr = ((const float4*)(msg + (size_t)p * 32))[q];
        acc.x += mr.x; acc.y += mr.y; acc.z += mr.z; acc.w += mr.w;
    }
    acc.x = fmaxf(acc.x, 0.f); acc.y = fmaxf(acc.y, 0.f);
    acc.z = fmaxf(acc.z, 0.f); acc.w = fmaxf(acc.w, 0.f);
    ((float4*)(h1 + (size_t)n * 32))[q] = acc;
}

// ---------------- reduce2: h2 = relu(segsum(msg) + h1@root2 + bias2) ---------
__global__ __launch_bounds__(256) void k_reduce2(
    const float* __restrict__ msg, const int* __restrict__ offs,
    const float* __restrict__ h1, const float* __restrict__ root,
    const float* __restrict__ bias, float* __restrict__ h2)
{
    __shared__ float s_r[512];   // [32][16]
    __shared__ float s_b[16];
    int tid = threadIdx.x;
    for (int i = tid; i < 512; i += 256) s_r[i] = root[i];
    if (tid < 16) s_b[tid] = bias[tid];
    __syncthreads();
    int gid = blockIdx.x * 256 + tid;
    int n = gid >> 2, q = gid & 3;
    int s = offs[n], e = offs[n + 1];
    float4 acc = make_float4(s_b[4*q], s_b[4*q+1], s_b[4*q+2], s_b[4*q+3]);
    const float4* s_r4 = (const float4*)s_r;
    const float* xp = h1 + (size_t)n * 32;
#pragma unroll
    for (int i = 0; i < 32; ++i) {
        float xi = xp[i];
        float4 w = s_r4[i*4 + q];
        acc.x += xi*w.x; acc.y += xi*w.y; acc.z += xi*w.z; acc.w += xi*w.w;
    }
    for (int p = s; p < e; ++p) {
        float4 mr = ((const float4*)(msg + (size_t)p * 16))[q];
        acc.x += mr.x; acc.y += mr.y; acc.z += mr.z; acc.w += mr.w;
    }
    acc.x = fmaxf(acc.x, 0.f); acc.y = fmaxf(acc.y, 0.f);
    acc.z = fmaxf(acc.z, 0.f); acc.w = fmaxf(acc.w, 0.f);
    ((float4*)(h2 + (size_t)n * 16))[q] = acc;
}

// ---------------- mean pool + concat + head ----------------------------------
__global__ __launch_bounds__(64) void k_head(
    const float* __restrict__ h2, const float* __restrict__ x_att,
    const int* __restrict__ goffs,
    const float* __restrict__ l1w, const float* __restrict__ l1b,
    const float* __restrict__ l2w, const float* __restrict__ l2b,
    float* __restrict__ out)
{
    int g = blockIdx.x;
    int lane = threadIdx.x;
    int s = goffs[g], e = goffs[g + 1];
    __shared__ float v[32];
    __shared__ float hmid[8];
    int f = lane & 15, sub = lane >> 4;
    float acc = 0.f;
    for (int i = s + sub; i < e; i += 4) acc += h2[(size_t)i*16 + f];
    acc += __shfl_xor(acc, 16);
    acc += __shfl_xor(acc, 32);
    float cnt = fmaxf((float)(e - s), 1.0f);
    if (lane < 16) {
        v[lane]      = acc / cnt;
        v[16 + lane] = x_att[g*16 + lane];
    }
    __syncthreads();
    if (lane < 8) {
        float a = l1b[lane];
#pragma unroll
        for (int i = 0; i < 32; ++i) a += v[i] * l1w[i*8 + lane];
        hmid[lane] = a;
    }
    __syncthreads();
    if (lane == 0) {
        float a = l2b[0];
#pragma unroll
        for (int j = 0; j < 8; ++j) a += hmid[j] * l2w[j];
        out[g] = a;
    }
}

extern "C" void kernel_launch(void* const* d_in, const int* in_sizes, int n_in,
                              void* d_out, int out_size, void* d_ws, size_t ws_size,
                              hipStream_t stream) {
    const float* x_p    = (const float*)d_in[0];
    const float* ea_p   = (const float*)d_in[2];
    const int*   ei     = (const int*)d_in[4];
    const int*   batch  = (const int*)d_in[5];
    const float* nn1_w1 = (const float*)d_in[6];
    const float* nn1_b1 = (const float*)d_in[7];
    const float* nn1_w2 = (const float*)d_in[8];
    const float* nn1_b2 = (const float*)d_in[9];
    const float* root1  = (const float*)d_in[10];
    const float* bias1  = (const float*)d_in[11];
    const float* nn2_w1 = (const float*)d_in[12];
    const float* nn2_b1 = (const float*)d_in[13];
    const float* nn2_w2 = (const float*)d_in[14];
    const float* nn2_b2 = (const float*)d_in[15];
    const float* root2  = (const float*)d_in[16];
    const float* bias2  = (const float*)d_in[17];
    const float* gw1    = (const float*)d_in[18];
    const float* gb1    = (const float*)d_in[19];
    const float* gw2    = (const float*)d_in[20];
    const float* gb2    = (const float*)d_in[21];
    const float* l1w    = (const float*)d_in[22];
    const float* l1b    = (const float*)d_in[23];
    const float* l2w    = (const float*)d_in[24];
    const float* l2b    = (const float*)d_in[25];

    // -------- workspace layout --------
    float*    h1     = (float*)d_ws;                     // NN*32
    float*    h2     = h1 + (size_t)NN * 32;             // NN*16
    float*    g_all  = h2 + (size_t)NN * 16;             // NN
    float*    x_att  = g_all + NN;                       // NG*16
    int*      goffs  = (int*)(x_att + (size_t)NG * 16);  // 2052
    int*      offs   = goffs + 2052;                     // 65540
    int*      cnt    = offs + 65540;                     // NN
    int*      bsum   = cnt + NN;                         // 256
    int*      boff   = bsum + 256;                       // 256
    int*      eperm  = boff + 256;                       // NE
    unsigned* bfrag1 = (unsigned*)(eperm + NE);          // 17*2*64*4 = 8704
    unsigned* bfrag2 = bfrag1 + 8704;                    // 8704
    float*    msg    = (float*)(bfrag2 + 8704);          // NE*32 (conv1) / NE*16 (conv2)

    // -------- attention pool path --------
    k_gate<<<NN/256, 256, 0, stream>>>(x_p, gw1, gb1, gw2, gb2, g_all);
    k_goffsets<<<(NG + 1 + 255)/256, 256, 0, stream>>>(batch, goffs);
    k_attpool<<<NG, 64, 0, stream>>>(x_p, g_all, goffs, x_att);

    // -------- CSR build over dst --------
    hipMemsetAsync(cnt, 0, (size_t)NN * sizeof(int), stream);
    k_hist<<<NE/256, 256, 0, stream>>>(ei, cnt);
    k_scan_blk<<<NN/256, 256, 0, stream>>>(cnt, offs, bsum);
    k_scan_top<<<1, 256, 0, stream>>>(bsum, boff);
    k_scan_add<<<NN/256, 256, 0, stream>>>(offs, boff);
    hipMemsetAsync(cnt, 0, (size_t)NN * sizeof(int), stream);
    k_scatter<<<NE/256, 256, 0, stream>>>(ei, offs, cnt, eperm);

    // -------- W fragment prep --------
    k_prep<<<68, 256, 0, stream>>>(nn1_w2, nn1_b2, nn2_w2, nn2_b2, bfrag1, bfrag2);

    // -------- conv1 + fused node update --------
    k_conv1<<<2048, 256, 0, stream>>>(x_p, ea_p, ei, eperm, nn1_w1, nn1_b1, bfrag1, msg);
    k_reduce1<<<NN*8/256, 256, 0, stream>>>(msg, offs, x_p, root1, bias1, h1);

    // -------- conv2 + fused node update --------
    k_conv2<<<4096, 256, 0, stream>>>(h1, ea_p, ei, eperm, nn2_w1, nn2_b1, bfrag2, msg);
    k_reduce2<<<NN*4/256, 256, 0, stream>>>(msg, offs, h1, root2, bias2, h2);

    // -------- head --------
    k_head<<<NG, 64, 0, stream>>>(h2, x_att, goffs, l1w, l1b, l2w, l2b, (float*)d_out);
}